// Round 5
// baseline (207.055 us; speedup 1.0000x reference)
//
#include <hip/hip_runtime.h>
#include <stdint.h>

// ---------------------------------------------------------------------------
// BinaryLinear: out[M,N] = x[M,K] @ sign(W[N,K])^T + bias[N]
// M=8192, K=2048, N=2048, fp32 in/out.
// Round 9: B (binary W) leaves LDS entirely — bit-plane + register expansion.
//   Evidence: 4 schedules all plateau 77-85us at MfmaUtil ~33%. Cycle budget
//   per CU per K-tile: MFMA ~2100 cyc, LDS b128 service ~2300 cyc (shared
//   per-CU pipe) -> LDS read traffic is the co-bottleneck. B is +-1: 1 bit.
//   - W preprocessed to bits [K/64][N][8B] (512 KB). Per K-tile each lane
//     loads u64 of its column's 64 k-bits (4 x dwordx2, L2-hot) and expands
//     to bf16 +-1 frags in registers (bf16 = 0x3F80 | bit<<15).
//   - LDS: A only, 3-slot ring (96 KB), global_load_lds width=16, stage
//     T+2 at phase 1; counted guards vmcnt(8)/(4) with 6-10 phase lag,
//     never drain-0 until the tail. Swizzle as R7/R8 (verified).
//   - Phase skeleton unchanged from R8 (passed): per mh-phase 4 ds_read_b128
//     -> s_barrier -> lgkmcnt(0) -> setprio(1) -> 16 MFMA -> setprio(0).
//   - Epilogue: direct stores (verified R5-R8).
// ---------------------------------------------------------------------------

typedef __bf16 bf16x8 __attribute__((ext_vector_type(8)));
typedef float f32x4 __attribute__((ext_vector_type(4)));

typedef const __attribute__((address_space(1))) void* gas_ptr;
typedef __attribute__((address_space(3))) void* lds_ptr;

__device__ __forceinline__ unsigned short f2bf_rne(float f) {
    unsigned int u = __builtin_bit_cast(unsigned int, f);
    u += 0x7fffu + ((u >> 16) & 1u);   // round-to-nearest-even
    return (unsigned short)(u >> 16);
}

// Merged prep.
//  blocks [0, nxB): x fp32 -> bf16 bits, 8/thread (verified R4 math).
//  blocks [nxB, ..): W fp32 -> sign bit-plane wbits[kt][n][kb], where
//    byte (kt,n,kb) bit j = (W[n][kt*64+kb*8+j] >= 0) ? 0 : 1.
//    Thread i = (kt*N + n)*8 + kb  (N=2048: kt=i>>14, n=(i>>3)&2047, kb=i&7).
__global__ __launch_bounds__(256) void prep_kernel(
    const float* __restrict__ x, const float* __restrict__ w,
    unsigned short* __restrict__ xb, unsigned char* __restrict__ wbits,
    int nx8, int nxB, int nw8, int K)
{
    const int b = blockIdx.x;
    if (b < nxB) {
        int i = b * 256 + threadIdx.x;
        if (i >= nx8) return;
        const float4* p = reinterpret_cast<const float4*>(x + (size_t)i * 8);
        float4 f0 = p[0], f1 = p[1];
        union { unsigned short s[8]; uint4 v; } o;
        o.s[0] = f2bf_rne(f0.x); o.s[1] = f2bf_rne(f0.y);
        o.s[2] = f2bf_rne(f0.z); o.s[3] = f2bf_rne(f0.w);
        o.s[4] = f2bf_rne(f1.x); o.s[5] = f2bf_rne(f1.y);
        o.s[6] = f2bf_rne(f1.z); o.s[7] = f2bf_rne(f1.w);
        *reinterpret_cast<uint4*>(xb + (size_t)i * 8) = o.v;
    } else {
        int i = (b - nxB) * 256 + threadIdx.x;
        if (i >= nw8) return;
        const int kt = i >> 14;            // N*8 = 16384
        const int n  = (i >> 3) & 2047;
        const int kb = i & 7;
        const float4* p = reinterpret_cast<const float4*>(
            w + (size_t)n * K + kt * 64 + kb * 8);
        float4 f0 = p[0], f1 = p[1];
        unsigned bt = 0;
        bt |= (f0.x >= 0.f) ? 0u : 1u;
        bt |= (f0.y >= 0.f) ? 0u : 2u;
        bt |= (f0.z >= 0.f) ? 0u : 4u;
        bt |= (f0.w >= 0.f) ? 0u : 8u;
        bt |= (f1.x >= 0.f) ? 0u : 16u;
        bt |= (f1.y >= 0.f) ? 0u : 32u;
        bt |= (f1.z >= 0.f) ? 0u : 64u;
        bt |= (f1.w >= 0.f) ? 0u : 128u;
        wbits[i] = (unsigned char)bt;
    }
}

#define WAITLGKM0 asm volatile("s_waitcnt lgkmcnt(0)")
#define WAITVM8   asm volatile("s_waitcnt vmcnt(8)")
#define WAITVM4   asm volatile("s_waitcnt vmcnt(4)")
#define SBAR      __builtin_amdgcn_s_barrier()

// A LDS: 3 slots x (256 rows x 64 bf16) = 96 KB, swizzled chunk =
// c ^ (((row>>2)&1)<<1) applied on global source (dest linear) and reads.
__global__ __launch_bounds__(512, 2) void gemm_bin_kernel(
    const unsigned short* __restrict__ A,   // bf16 bits [M][K]
    const unsigned char*  __restrict__ Wb,  // bits [K/64][N][8]
    const float* __restrict__ bias,         // [N]
    float* __restrict__ C,                  // [M][N]
    int M, int N, int K)
{
    __shared__ __align__(16) unsigned char smem_raw[98304];
    unsigned short* const sm = (unsigned short*)smem_raw;

    const int tid  = threadIdx.x;
    const int lane = tid & 63;
    const int wave = tid >> 6;    // 0..7
    const int wm   = wave >> 2;   // 0..1  (M half: 128 rows)
    const int wn   = wave & 3;    // 0..3  (N quarter: 64 cols)
    const int bm   = blockIdx.y;  // 32
    const int bn   = blockIdx.x;  // 8

    const unsigned short* __restrict__ Agb = A + (size_t)(bm * 256) * K;

    const int r15 = lane & 15;    // frag row (A) / col (B)
    const int kc  = lane >> 4;    // k-chunk 0..3 within K=32 slice
    const int sw  = ((r15 >> 2) & 1) << 1;

    const int baseA0 = wm * 8192 + r15 * 64 + ((kc    ) ^ sw) * 8;
    const int baseA1 = wm * 8192 + r15 * 64 + ((kc + 4) ^ sw) * 8;

    // A staging: 4 x 16B chunks/thread (2048 chunks = 256 rows x 8).
    int gsoff[4], ldoff[4];
#pragma unroll
    for (int j = 0; j < 4; ++j) {
        const int g  = j * 512 + tid;
        const int rl = g >> 3;
        const int c  = (g & 7) ^ (((rl >> 2) & 1) << 1);
        gsoff[j] = rl * K + c * 8;
        ldoff[j] = g * 8;
    }

    const int colb = bn * 256 + wn * 64;
    float bv[4];
#pragma unroll
    for (int nf = 0; nf < 4; ++nf) {
        bv[nf] = bias[colb + nf * 16 + r15];
        asm volatile("" :: "v"(bv[nf]));
    }

    f32x4 acc[8][4];
#pragma unroll
    for (int m = 0; m < 8; ++m)
#pragma unroll
        for (int n = 0; n < 4; ++n)
#pragma unroll
            for (int r = 0; r < 4; ++r) acc[m][n][r] = 0.f;

    uint2 bitsCur[4], bitsNxt[4];
    bf16x8 bfr[4][2];
    const int shb = kc * 8;

    auto loadbits = [&](int kt, uint2* dst) {
        const unsigned char* base = Wb + (size_t)kt * ((size_t)N * 8);
#pragma unroll
        for (int nf = 0; nf < 4; ++nf)
            dst[nf] = *reinterpret_cast<const uint2*>(
                base + (size_t)(colb + nf * 16 + r15) * 8);
    };
    auto stageA = [&](int T, int slot) {
        unsigned short* d = sm + slot * 16384;
        const unsigned short* g = Agb + (size_t)T * 64;
#pragma unroll
        for (int j = 0; j < 4; ++j)
            __builtin_amdgcn_global_load_lds((gas_ptr)(g + gsoff[j]),
                                             (lds_ptr)(d + ldoff[j]), 16, 0, 0);
    };
    auto expand = [&]() {
#pragma unroll
        for (int nf = 0; nf < 4; ++nf)
#pragma unroll
            for (int kk = 0; kk < 2; ++kk) {
                unsigned w32 = kk ? bitsCur[nf].y : bitsCur[nf].x;
                unsigned bbits = (w32 >> shb) & 0xffu;
                union { unsigned u[4]; bf16x8 v; } o;
                o.u[0] = 0x3F803F80u | ((bbits &   1u) << 15) | ((bbits &   2u) << 30);
                o.u[1] = 0x3F803F80u | ((bbits &   4u) << 13) | ((bbits &   8u) << 28);
                o.u[2] = 0x3F803F80u | ((bbits &  16u) << 11) | ((bbits &  32u) << 26);
                o.u[3] = 0x3F803F80u | ((bbits &  64u) <<  9) | ((bbits & 128u) << 24);
                bfr[nf][kk] = o.v;
            }
    };

    const int KT = K >> 6;   // 32 K-tiles of 64

    // Prologue: bits(0) first (so its auto-wait is counted, not drain-0),
    // then stage(0), stage(1); vmcnt(4) certifies stage(0) (allows stage(1)).
    loadbits(0, bitsCur);
    stageA(0, 0);
    stageA(1, 1);
    WAITVM4;
    SBAR;

    int sc = 0, sp = 2;   // compute slot (T%3), prefetch slot ((T+2)%3)
    for (int T = 0; T < KT; ++T) {
        const unsigned short* bb = sm + sc * 16384;
#pragma unroll
        for (int mh = 0; mh < 4; ++mh) {
            if (mh == 0) expand();
            bf16x8 af[2][2];
#pragma unroll
            for (int mi = 0; mi < 2; ++mi) {
                af[mi][0] = *reinterpret_cast<const bf16x8*>(bb + baseA0 + (mh * 2 + mi) * 1024);
                af[mi][1] = *reinterpret_cast<const bf16x8*>(bb + baseA1 + (mh * 2 + mi) * 1024);
            }
            if (mh == 0 && T + 1 < KT) loadbits(T + 1, bitsNxt);
            if (mh == 1 && T + 2 < KT) stageA(T + 2, sp);
            SBAR;
            WAITLGKM0;
            __builtin_amdgcn_s_setprio(1);
#pragma unroll
            for (int kk = 0; kk < 2; ++kk)
#pragma unroll
                for (int mi = 0; mi < 2; ++mi)
#pragma unroll
                    for (int nf = 0; nf < 4; ++nf)
                        acc[mh * 2 + mi][nf] = __builtin_amdgcn_mfma_f32_16x16x32_bf16(
                            af[mi][kk], bfr[nf][kk], acc[mh * 2 + mi][nf], 0, 0, 0);
            __builtin_amdgcn_s_setprio(0);
            if (mh == 3) {
                // Certify stage(T+1) for next tile's reads. Steady: 8 newer
                // loads allowed (bits(T+1)+stage(T+2)); T=KT-2: 4 (bits only);
                // T=KT-1: nothing to certify.
                if (T < KT - 2)       { WAITVM8; }
                else if (T == KT - 2) { WAITVM4; }
            }
            SBAR;
        }
#pragma unroll
        for (int nf = 0; nf < 4; ++nf) bitsCur[nf] = bitsNxt[nf];
        sc = (sc == 2) ? 0 : sc + 1;
        sp = (sp == 2) ? 0 : sp + 1;
    }

    // Epilogue: direct stores. 16x16 C/D: col = lane&15, row = (lane>>4)*4+reg.
    const int row0 = bm * 256 + wm * 128 + kc * 4;
#pragma unroll
    for (int mf = 0; mf < 8; ++mf)
#pragma unroll
        for (int nf = 0; nf < 4; ++nf) {
            float* cp = C + (size_t)(row0 + mf * 16) * N + colb + nf * 16 + r15;
#pragma unroll
            for (int r = 0; r < 4; ++r)
                cp[(size_t)r * N] = acc[mf][nf][r] + bv[nf];
        }
}

extern "C" void kernel_launch(void* const* d_in, const int* in_sizes, int n_in,
                              void* d_out, int out_size, void* d_ws, size_t ws_size,
                              hipStream_t stream) {
    const float* x    = (const float*)d_in[0];   // [M, K]
    const float* w    = (const float*)d_in[1];   // [N, K]
    const float* bias = (const float*)d_in[2];   // [N]
    float* out = (float*)d_out;

    const int K = 2048;                 // IN
    const int N = in_sizes[2];          // OUT = 2048
    const int M = in_sizes[0] / K;      // 8192

    unsigned short* xb = (unsigned short*)d_ws;            // [M,K] bf16: 32 MB
    unsigned char* wbits = (unsigned char*)(xb + (size_t)M * K);  // 512 KB

    const int nx8 = (M * K) / 8;
    const int nw8 = (N * K) / 8;
    const int nxB = (nx8 + 255) / 256;
    const int nwB = (nw8 + 255) / 256;
    prep_kernel<<<nxB + nwB, 256, 0, stream>>>(x, w, xb, wbits, nx8, nxB, nw8, K);

    dim3 grid(N / 256, M / 256);        // (8, 32) = 256 blocks, 1/CU
    gemm_bin_kernel<<<grid, 512, 0, stream>>>(xb, wbits, bias, out, M, N, K);
}

// Round 6
// 189.554 us; speedup vs baseline: 1.0923x; 1.0923x over previous
//
#include <hip/hip_runtime.h>
#include <stdint.h>

// ---------------------------------------------------------------------------
// BinaryLinear: out[M,N] = x[M,K] @ sign(W[N,K])^T + bias[N]
// M=8192, K=2048, N=2048, fp32 in/out.
// Round 10: drain-free K32-panel ring. Evidence: every prior variant carried
// a once-per-tile vmcnt(0) (or clobber-induced drains) => 33% MfmaUtil
// plateau; cycle model says drain+restage ~1500cyc/tile vs 64% ideal.
//   - 256x256 tile, 512 thr (8 waves 2Mx4N), 16x16x32 MFMA, acc f32x4[8][4].
//   - LDS: 4-slot ring of K=32 panels (A 256x32 + B 256x32 = 32KB/slot,
//     128KB total). Step s computes panels in slot s%4; stages A(s+2) in
//     phase 1, B(s+2) in phase 2 into slot (s+2)%4 (2 gload_lds each).
//   - End-of-step s_waitcnt vmcnt(4): certifies step s+1 (staged 2 phases
//     ago, ~1200cyc lag => stall-free), leaves step s+2 in flight. NEVER
//     drains below 4 until the tail (vmcnt(0) only at step NS-2, 2-step lag
//     = free). No other vmcnt anywhere.
//   - Phase: {ds_reads || 2 gload_lds} -> s_barrier -> lgkmcnt(0) ->
//     setprio(1) -> 16 MFMA -> setprio(0) -> [end-of-step wait] -> s_barrier.
//     Bare barriers (no clobbers), no sched_barrier.
//   - Swizzle: 32-bf16 rows, phys_chunk = c ^ ((row>>1)&3) on global source
//     (LDS dest linear) and on ds_read addresses (both-sides, rule #21).
//   - Epilogue: direct stores (harness-verified R5-R9).
// Prep: merged single kernel (harness-verified R8 math).
// ---------------------------------------------------------------------------

typedef __bf16 bf16x8 __attribute__((ext_vector_type(8)));
typedef float f32x4 __attribute__((ext_vector_type(4)));

typedef const __attribute__((address_space(1))) void* gas_ptr;
typedef __attribute__((address_space(3))) void* lds_ptr;

__device__ __forceinline__ unsigned short f2bf_rne(float f) {
    unsigned int u = __builtin_bit_cast(unsigned int, f);
    u += 0x7fffu + ((u >> 16) & 1u);   // round-to-nearest-even
    return (unsigned short)(u >> 16);
}

__global__ __launch_bounds__(256) void prep_kernel(
    const float* __restrict__ x, const float* __restrict__ w,
    unsigned short* __restrict__ xb, unsigned short* __restrict__ wb,
    int nx8, int nxB, int nw4)
{
    const int b = blockIdx.x;
    if (b < nxB) {
        int i = b * 256 + threadIdx.x;
        if (i >= nx8) return;
        const float4* p = reinterpret_cast<const float4*>(x + (size_t)i * 8);
        float4 f0 = p[0], f1 = p[1];
        union { unsigned short s[8]; uint4 v; } o;
        o.s[0] = f2bf_rne(f0.x); o.s[1] = f2bf_rne(f0.y);
        o.s[2] = f2bf_rne(f0.z); o.s[3] = f2bf_rne(f0.w);
        o.s[4] = f2bf_rne(f1.x); o.s[5] = f2bf_rne(f1.y);
        o.s[6] = f2bf_rne(f1.z); o.s[7] = f2bf_rne(f1.w);
        *reinterpret_cast<uint4*>(xb + (size_t)i * 8) = o.v;
    } else {
        int i = (b - nxB) * 256 + threadIdx.x;
        if (i >= nw4) return;
        float4 f = reinterpret_cast<const float4*>(w)[i];
        union { unsigned short s[4]; uint2 v; } o;
        o.s[0] = (f.x >= 0.f) ? 0x3F80u : 0xBF80u;
        o.s[1] = (f.y >= 0.f) ? 0x3F80u : 0xBF80u;
        o.s[2] = (f.z >= 0.f) ? 0x3F80u : 0xBF80u;
        o.s[3] = (f.w >= 0.f) ? 0x3F80u : 0xBF80u;
        reinterpret_cast<uint2*>(wb)[i] = o.v;
    }
}

#define WAITLGKM0 asm volatile("s_waitcnt lgkmcnt(0)")
#define WAITVM4   asm volatile("s_waitcnt vmcnt(4)")
#define WAITVM0   asm volatile("s_waitcnt vmcnt(0)")
#define SBAR      __builtin_amdgcn_s_barrier()

__global__ __launch_bounds__(512, 2) void gemm_bin_kernel(
    const unsigned short* __restrict__ A,   // bf16 bits [M][K]
    const unsigned short* __restrict__ B,   // bf16 bits [N][K]
    const float* __restrict__ bias,         // [N]
    float* __restrict__ C,                  // [M][N]
    int M, int N, int K)
{
    // 4 slots x (A 256x32 + B 256x32) bf16 = 4 x 32KB = 128KB.
    __shared__ __align__(16) unsigned char smem_raw[131072];
    unsigned short* const sm = (unsigned short*)smem_raw;

    const int tid  = threadIdx.x;
    const int lane = tid & 63;
    const int wave = tid >> 6;    // 0..7
    const int wm   = wave >> 2;   // 0..1  (M half: 128 rows)
    const int wn   = wave & 3;    // 0..3  (N quarter: 64 cols)
    const int bm   = blockIdx.y;  // 32
    const int bn   = blockIdx.x;  // 8

    const unsigned short* __restrict__ Agb = A + (size_t)(bm * 256) * K;
    const unsigned short* __restrict__ Bgb = B + (size_t)(bn * 256) * K;

    const int r15 = lane & 15;    // frag row (A) / col (B)
    const int kc  = lane >> 4;    // k-chunk 0..3 (k = kc*8..+8)

    // Frag read bases (ushort, slot-relative). Panel row stride = 32 bf16.
    int baseA[2][4], baseB[4];
#pragma unroll
    for (int mh = 0; mh < 2; ++mh)
#pragma unroll
        for (int mf = 0; mf < 4; ++mf) {
            const int row = wm * 128 + mh * 64 + mf * 16 + r15;
            baseA[mh][mf] = row * 32 + (kc ^ ((row >> 1) & 3)) * 8;
        }
#pragma unroll
    for (int nf = 0; nf < 4; ++nf) {
        const int row = wn * 64 + nf * 16 + r15;
        baseB[nf] = 8192 + row * 32 + (kc ^ ((row >> 1) & 3)) * 8;
    }

    // Staging: panel = 256 rows x 4 chunks(16B) = 1024 chunks; 2/thread.
    // LDS dest linear; global source column pre-swizzled (involution).
    int gsoff[2], ldoff[2];
#pragma unroll
    for (int j = 0; j < 2; ++j) {
        const int g  = j * 512 + tid;
        const int rl = g >> 2;
        const int c  = (g & 3) ^ ((rl >> 1) & 3);
        gsoff[j] = rl * K + c * 8;
        ldoff[j] = g * 8;
    }

    const int colb = bn * 256 + wn * 64;
    float bv[4];
#pragma unroll
    for (int nf = 0; nf < 4; ++nf) {
        bv[nf] = bias[colb + nf * 16 + r15];
        asm volatile("" :: "v"(bv[nf]));
    }

    f32x4 acc[8][4];
#pragma unroll
    for (int m = 0; m < 8; ++m)
#pragma unroll
        for (int n = 0; n < 4; ++n)
#pragma unroll
            for (int r = 0; r < 4; ++r) acc[m][n][r] = 0.f;

    auto stageP = [&](const unsigned short* g, unsigned short* d) {
#pragma unroll
        for (int j = 0; j < 2; ++j)
            __builtin_amdgcn_global_load_lds((gas_ptr)(g + gsoff[j]),
                                             (lds_ptr)(d + ldoff[j]), 16, 0, 0);
    };

    const int NS = K >> 5;   // 64 K-steps of 32

    // Prologue: stage steps 0 and 1 (A+B each); certify step 0 (vmcnt(4)
    // leaves step 1's 4 loads in flight — no drain).
    stageP(Agb,      sm);
    stageP(Bgb,      sm + 8192);
    stageP(Agb + 32, sm + 16384);
    stageP(Bgb + 32, sm + 16384 + 8192);
    WAITVM4;
    SBAR;

#pragma unroll 4
    for (int s = 0; s < NS; ++s) {
        const unsigned short* us = sm + (s & 3) * 16384;
        unsigned short* sp = sm + ((s + 2) & 3) * 16384;
        const int pf = (s + 2 < NS);

        // ---- phase 1: B frags (4) + A-mh0 frags (4) || stage A(s+2) ----
        bf16x8 bfr[4], afr[4];
#pragma unroll
        for (int nf = 0; nf < 4; ++nf)
            bfr[nf] = *reinterpret_cast<const bf16x8*>(us + baseB[nf]);
#pragma unroll
        for (int mf = 0; mf < 4; ++mf)
            afr[mf] = *reinterpret_cast<const bf16x8*>(us + baseA[0][mf]);
        if (pf) stageP(Agb + (size_t)(s + 2) * 32, sp);
        SBAR;
        WAITLGKM0;
        __builtin_amdgcn_s_setprio(1);
#pragma unroll
        for (int mf = 0; mf < 4; ++mf)
#pragma unroll
            for (int nf = 0; nf < 4; ++nf)
                acc[mf][nf] = __builtin_amdgcn_mfma_f32_16x16x32_bf16(
                    afr[mf], bfr[nf], acc[mf][nf], 0, 0, 0);
        __builtin_amdgcn_s_setprio(0);
        SBAR;

        // ---- phase 2: A-mh1 frags (4) || stage B(s+2); end-of-step wait ----
#pragma unroll
        for (int mf = 0; mf < 4; ++mf)
            afr[mf] = *reinterpret_cast<const bf16x8*>(us + baseA[1][mf]);
        if (pf) stageP(Bgb + (size_t)(s + 2) * 32, sp + 8192);
        SBAR;
        WAITLGKM0;
        __builtin_amdgcn_s_setprio(1);
#pragma unroll
        for (int mf = 0; mf < 4; ++mf)
#pragma unroll
            for (int nf = 0; nf < 4; ++nf)
                acc[4 + mf][nf] = __builtin_amdgcn_mfma_f32_16x16x32_bf16(
                    afr[mf], bfr[nf], acc[4 + mf][nf], 0, 0, 0);
        __builtin_amdgcn_s_setprio(0);
        if (pf)                 { WAITVM4; }   // certify s+1; s+2 stays in flight
        else if (s + 1 < NS)    { WAITVM0; }   // tail: certify last step (2-step lag)
        SBAR;
    }

    // Epilogue: direct stores. 16x16 C/D: col = lane&15, row = (lane>>4)*4+reg.
    const int row0 = bm * 256 + wm * 128 + kc * 4;
#pragma unroll
    for (int mf = 0; mf < 8; ++mf)
#pragma unroll
        for (int nf = 0; nf < 4; ++nf) {
            float* cp = C + (size_t)(row0 + mf * 16) * N + colb + nf * 16 + r15;
#pragma unroll
            for (int r = 0; r < 4; ++r)
                cp[(size_t)r * N] = acc[mf][nf][r] + bv[nf];
        }
}

extern "C" void kernel_launch(void* const* d_in, const int* in_sizes, int n_in,
                              void* d_out, int out_size, void* d_ws, size_t ws_size,
                              hipStream_t stream) {
    const float* x    = (const float*)d_in[0];   // [M, K]
    const float* w    = (const float*)d_in[1];   // [N, K]
    const float* bias = (const float*)d_in[2];   // [N]
    float* out = (float*)d_out;

    const int K = 2048;                 // IN
    const int N = in_sizes[2];          // OUT = 2048
    const int M = in_sizes[0] / K;      // 8192

    unsigned short* xb = (unsigned short*)d_ws;   // [M,K] bf16: 32 MB
    unsigned short* wb = xb + (size_t)M * K;      // [N,K] bf16 +-1: 8 MB

    const int nx8 = (M * K) / 8;
    const int nw4 = (N * K) / 4;
    const int nxB = (nx8 + 255) / 256;
    const int nwB = (nw4 + 255) / 256;
    prep_kernel<<<nxB + nwB, 256, 0, stream>>>(x, w, xb, wb, nx8, nxB, nw4);

    dim3 grid(N / 256, M / 256);        // (8, 32) = 256 blocks, 1/CU
    gemm_bin_kernel<<<grid, 512, 0, stream>>>(xb, wb, bias, out, M, N, K);
}